// Round 7
// baseline (418.216 us; speedup 1.0000x reference)
//
#include <hip/hip_runtime.h>

#define N_NODES 50000
#define N_EDGES 800000
#define F 64
#define NROWS (N_NODES * 3)          // 150000 node-(v) rows
#define EROWS (N_EDGES * 3)          // 2400000 edge-(v) rows
#define NPX (N_NODES * 3 * F)        // 9,600,000 floats (px_out size)
#define NMM_BLOCKS ((NROWS + 63) / 64)         // 2344
#define HIST_BLOCKS ((N_EDGES + 1023) / 1024)  // 782

typedef float floatx4 __attribute__((ext_vector_type(4)));
typedef unsigned short ushortx8 __attribute__((ext_vector_type(8)));

__device__ __forceinline__ unsigned short f2bf(float f) {
  unsigned int u = __float_as_uint(f);
  return (unsigned short)((u + 0x7FFFu + ((u >> 16) & 1u)) >> 16);
}
__device__ __forceinline__ float bf2f(unsigned short h) {
  return __uint_as_float(((unsigned int)h) << 16);
}

// --- chained 64x64 matmul: Out = (W_ii @ Wx) @ W_pp, one product per block ---
__global__ __launch_bounds__(256) void mm64_chain(
    const float* __restrict__ W_ii, const float* __restrict__ W_i,
    const float* __restrict__ W_j, const float* __restrict__ W_pp,
    float* __restrict__ Bi, float* __restrict__ Bj) {
  const float* Wx = (blockIdx.x == 0) ? W_i : W_j;
  float* Out = (blockIdx.x == 0) ? Bi : Bj;
  __shared__ float As[64][65];
  __shared__ float Bs[64][65];
  __shared__ float Ps[64][65];
  int t = threadIdx.x;
  for (int k = 0; k < 16; ++k) {
    int idx = t + 256 * k;
    As[idx >> 6][idx & 63] = W_ii[idx];
    Bs[idx >> 6][idx & 63] = Wx[idx];
    Ps[idx >> 6][idx & 63] = W_pp[idx];
  }
  __syncthreads();
  int g = t >> 2, f0 = (t & 3) * 16;
  float acc[16];
  #pragma unroll
  for (int j = 0; j < 16; ++j) acc[j] = 0.f;
  for (int k = 0; k < 64; ++k) {
    float a = As[g][k];
    #pragma unroll
    for (int j = 0; j < 16; ++j) acc[j] += a * Bs[k][f0 + j];
  }
  __syncthreads();
  #pragma unroll
  for (int j = 0; j < 16; ++j) As[g][f0 + j] = acc[j];   // As = W_ii @ Wx
  __syncthreads();
  #pragma unroll
  for (int j = 0; j < 16; ++j) acc[j] = 0.f;
  for (int k = 0; k < 64; ++k) {
    float a = As[g][k];
    #pragma unroll
    for (int j = 0; j < 16; ++j) acc[j] += a * Ps[k][f0 + j];
  }
  for (int j = 0; j < 16; ++j) Out[g * 64 + f0 + j] = acc[j];
}

// --- node GEMM (blocks 0..NMM-1) + idx_i histogram (remaining blocks) ---
// ybi[r,:] = px@Bi^T (bf16) ; ybj[r,:] = px@Bj^T (bf16)
__global__ __launch_bounds__(256) void node_mm_hist(
    const float* __restrict__ px, const float* __restrict__ Bi,
    const float* __restrict__ Bj, unsigned short* __restrict__ ybi,
    unsigned short* __restrict__ ybj,
    const int* __restrict__ idx_i, int* __restrict__ cnt) {
  __shared__ float pxs[64][68];
  __shared__ float Bs[128][68];    // rows 0..63 = Bi, 64..127 = Bj
  if (blockIdx.x >= NMM_BLOCKS) {
    int b = blockIdx.x - NMM_BLOCKS;
    int base = b * 1024 + threadIdx.x;
    #pragma unroll
    for (int k = 0; k < 4; ++k) {
      int e = base + k * 256;
      if (e < N_EDGES) atomicAdd(&cnt[idx_i[e]], 1);
    }
    return;
  }
  int t = threadIdx.x;
  int r0 = blockIdx.x * 64;
  #pragma unroll
  for (int k = 0; k < 8; ++k) {
    int idx = t + 256 * k;
    int row = idx >> 4, c4 = (idx & 15) * 4;
    const float* src = (row < 64) ? (Bi + row * 64 + c4) : (Bj + (row - 64) * 64 + c4);
    *(float4*)&Bs[row][c4] = *(const float4*)src;
  }
  #pragma unroll
  for (int k = 0; k < 4; ++k) {
    int idx = t + 256 * k;
    int lr = idx >> 4, c4 = (idx & 15) * 4;
    float4 v = make_float4(0.f, 0.f, 0.f, 0.f);
    if (r0 + lr < NROWS) v = *(const float4*)(px + (size_t)(r0 + lr) * 64 + c4);
    *(float4*)&pxs[lr][c4] = v;
  }
  __syncthreads();
  int q = t & 31;
  int rg = t >> 5;
  float acc[8][4];
  #pragma unroll
  for (int r = 0; r < 8; ++r)
    #pragma unroll
    for (int j = 0; j < 4; ++j) acc[r][j] = 0.f;
  #pragma unroll 4
  for (int fc = 0; fc < 16; ++fc) {
    float4 b[4];
    #pragma unroll
    for (int j = 0; j < 4; ++j) b[j] = *(const float4*)&Bs[4 * q + j][fc * 4];
    #pragma unroll
    for (int r = 0; r < 8; ++r) {
      float4 p = *(const float4*)&pxs[rg * 8 + r][fc * 4];
      #pragma unroll
      for (int j = 0; j < 4; ++j)
        acc[r][j] += p.x * b[j].x + p.y * b[j].y + p.z * b[j].z + p.w * b[j].w;
    }
  }
  #pragma unroll
  for (int r = 0; r < 8; ++r) {
    int grow = r0 + rg * 8 + r;
    if (grow >= NROWS) continue;
    ushort4 h;
    h.x = f2bf(acc[r][0]); h.y = f2bf(acc[r][1]);
    h.z = f2bf(acc[r][2]); h.w = f2bf(acc[r][3]);
    if (q < 16) *(ushort4*)(ybi + (size_t)grow * 64 + q * 4) = h;
    else        *(ushort4*)(ybj + (size_t)grow * 64 + (q - 16) * 4) = h;
  }
}

// --- CSR build step 2: exclusive scan, 8 elems/thread (single block) ---
__global__ __launch_bounds__(1024) void scan_kernel(
    const int* __restrict__ cnt, int* __restrict__ offs, int* __restrict__ cursor) {
  __shared__ int wsum[16];
  __shared__ int s_carry;
  int t = threadIdx.x, w = t >> 6, l = t & 63;
  if (t == 0) { s_carry = 0; offs[0] = 0; }
  __syncthreads();
  for (int base = 0; base < N_NODES; base += 8192) {
    int i0 = base + t * 8;
    int x[8];
    if (i0 + 7 < N_NODES) {
      int4 a = *(const int4*)(cnt + i0);
      int4 b = *(const int4*)(cnt + i0 + 4);
      x[0] = a.x; x[1] = a.y; x[2] = a.z; x[3] = a.w;
      x[4] = b.x; x[5] = b.y; x[6] = b.z; x[7] = b.w;
    } else {
      #pragma unroll
      for (int k = 0; k < 8; ++k) x[k] = (i0 + k < N_NODES) ? cnt[i0 + k] : 0;
    }
    int incl[8];
    int p = 0;
    #pragma unroll
    for (int k = 0; k < 8; ++k) { p += x[k]; incl[k] = p; }
    int tsum = p;
    int ts = tsum;
    #pragma unroll
    for (int off = 1; off < 64; off <<= 1) {
      int y = __shfl_up(ts, off, 64);
      if (l >= off) ts += y;
    }
    if (l == 63) wsum[w] = ts;
    __syncthreads();
    if (t < 16) {
      int ws_ = wsum[t];
      int si = ws_;
      #pragma unroll
      for (int off = 1; off < 16; off <<= 1) {
        int y = __shfl_up(si, off, 16);
        if (t >= off) si += y;
      }
      wsum[t] = si - ws_;          // exclusive wave base
    }
    __syncthreads();
    int basev = s_carry + wsum[w] + (ts - tsum);
    #pragma unroll
    for (int k = 0; k < 8; ++k) {
      int i = i0 + k;
      if (i < N_NODES) {
        int it = basev + incl[k];
        offs[i + 1] = it;
        cursor[i] = it - x[k];
      }
    }
    __syncthreads();
    if (t == 1023) s_carry = basev + tsum;
    __syncthreads();
  }
}

// --- Kernel A: edge-order streaming ix + fused CSR scatter ---
// 8 threads per (e,v) row; wave covers 8 rows = 2KB contiguous ix write.
__global__ __launch_bounds__(256) void edge_stream_kernel(
    const int* __restrict__ idx_i, const int* __restrict__ idx_j,
    const float* __restrict__ diff,
    const unsigned short* __restrict__ ybi, const unsigned short* __restrict__ ybj,
    float* __restrict__ ix_out,
    int* __restrict__ cursor, int* __restrict__ pnj, float* __restrict__ pdiff) {
  unsigned int gid = blockIdx.x * 256 + threadIdx.x;   // < EROWS*8
  int row = gid >> 3;                 // (e,v) row
  int e = row / 3;
  int v = row - e * 3;
  int fo = (gid & 7) * 8;             // feature octet
  int ni = idx_i[e];
  int nj = idx_j[e];
  float d = diff[row];
  const ushortx8 a = *(const ushortx8*)(ybi + ((size_t)ni * 3 + v) * 64 + fo);
  const ushortx8 b = *(const ushortx8*)(ybj + ((size_t)nj * 3 + v) * 64 + fo);
  floatx4 r0, r1;
  r0.x = d * (bf2f(a[0]) + bf2f(b[0]));
  r0.y = d * (bf2f(a[1]) + bf2f(b[1]));
  r0.z = d * (bf2f(a[2]) + bf2f(b[2]));
  r0.w = d * (bf2f(a[3]) + bf2f(b[3]));
  r1.x = d * (bf2f(a[4]) + bf2f(b[4]));
  r1.y = d * (bf2f(a[5]) + bf2f(b[5]));
  r1.z = d * (bf2f(a[6]) + bf2f(b[6]));
  r1.w = d * (bf2f(a[7]) + bf2f(b[7]));
  float* dst = ix_out + (size_t)row * 64 + fo;
  __builtin_nontemporal_store(r0, (floatx4*)dst);
  __builtin_nontemporal_store(r1, (floatx4*)(dst + 4));
  // fused CSR scatter: one thread per edge
  if (((gid & 7) == 0) && (v == 0)) {
    int pos = atomicAdd(&cursor[ni], 1);
    pnj[pos] = nj;
    pdiff[pos * 3 + 0] = d;            // v==0 → d = diff[e*3+0]
    pdiff[pos * 3 + 1] = diff[row + 1];
    pdiff[pos * 3 + 2] = diff[row + 2];
  }
}

// --- Kernel B: per (node,v) wave; gather ybj, accumulate px_out in regs ---
__global__ __launch_bounds__(192) void node_accum_kernel(
    const int* __restrict__ offs, const int* __restrict__ pnj,
    const float* __restrict__ pdiff,
    const unsigned short* __restrict__ ybi, const unsigned short* __restrict__ ybj,
    float* __restrict__ px_out) {
  int n = blockIdx.x;
  int v = threadIdx.x >> 6;          // 0..2 (one wave per v)
  int lane = threadIdx.x & 63;
  int s = lane >> 4;                 // edge slot 0..3
  int fq = (lane & 15) * 4;          // feature quad
  int start = offs[n], end = offs[n + 1];
  const ushort4 yw = *(const ushort4*)(ybi + ((size_t)n * 3 + v) * 64 + fq);
  float4 yiv = make_float4(bf2f(yw.x), bf2f(yw.y), bf2f(yw.z), bf2f(yw.w));
  float4 acc = make_float4(0.f, 0.f, 0.f, 0.f);
  float sum_d = 0.f;

  for (int p = start + s; p < end; p += 4) {
    int nj  = pnj[p];                        // linear (L1/L2)
    float d = pdiff[p * 3 + v];              // linear-ish
    const ushort4 w = *(const ushort4*)(ybj + ((size_t)nj * 3 + v) * 64 + fq);
    acc.x += d * bf2f(w.x); acc.y += d * bf2f(w.y);
    acc.z += d * bf2f(w.z); acc.w += d * bf2f(w.w);
    sum_d += d;
  }
  #pragma unroll
  for (int mm = 16; mm < 64; mm <<= 1) {
    acc.x += __shfl_xor(acc.x, mm, 64);
    acc.y += __shfl_xor(acc.y, mm, 64);
    acc.z += __shfl_xor(acc.z, mm, 64);
    acc.w += __shfl_xor(acc.w, mm, 64);
    sum_d += __shfl_xor(sum_d, mm, 64);
  }
  if (s == 0) {
    float4 o = make_float4(yiv.x * sum_d + acc.x, yiv.y * sum_d + acc.y,
                           yiv.z * sum_d + acc.z, yiv.w * sum_d + acc.w);
    *(float4*)(px_out + ((size_t)n * 3 + v) * 64 + fq) = o;
  }
}

extern "C" void kernel_launch(void* const* d_in, const int* in_sizes, int n_in,
                              void* d_out, int out_size, void* d_ws, size_t ws_size,
                              hipStream_t stream) {
  const int*   idx_i = (const int*)d_in[0];
  const int*   idx_j = (const int*)d_in[1];
  const float* px    = (const float*)d_in[2];
  const float* diff  = (const float*)d_in[3];
  const float* W_pp  = (const float*)d_in[4];
  const float* W_i   = (const float*)d_in[5];
  const float* W_j   = (const float*)d_in[6];
  const float* W_ii  = (const float*)d_in[7];

  float* px_out = (float*)d_out;              // [50000,3,64]
  float* ix_out = (float*)d_out + NPX;        // [800000,3,64]

  unsigned short* ybi = (unsigned short*)d_ws;             // [150000,64] bf16
  unsigned short* ybj = ybi + (size_t)NPX;                 // [150000,64] bf16
  float* Bi = (float*)(ybj + (size_t)NPX);
  float* Bj = Bi + 4096;
  int* cnt    = (int*)(Bj + 4096);             // [50000]
  int* offs   = cnt + N_NODES;                 // [50001]
  int* cursor = offs + N_NODES + 1;            // [50000]
  int* pnj    = cursor + N_NODES;              // [800000]
  float* pdiff = (float*)(pnj + N_EDGES);      // [800000*3]

  (void)hipMemsetAsync(cnt, 0, N_NODES * sizeof(int), stream);

  // Bi = W_ii @ W_i @ W_pp ; Bj = W_ii @ W_j @ W_pp
  mm64_chain<<<2, 256, 0, stream>>>(W_ii, W_i, W_j, W_pp, Bi, Bj);

  node_mm_hist<<<NMM_BLOCKS + HIST_BLOCKS, 256, 0, stream>>>(
      px, Bi, Bj, ybi, ybj, idx_i, cnt);

  scan_kernel<<<1, 1024, 0, stream>>>(cnt, offs, cursor);

  edge_stream_kernel<<<(EROWS * 8) / 256, 256, 0, stream>>>(
      idx_i, idx_j, diff, ybi, ybj, ix_out, cursor, pnj, pdiff);

  node_accum_kernel<<<N_NODES, 192, 0, stream>>>(offs, pnj, pdiff,
                                                 ybi, ybj, px_out);
}

// Round 8
// 319.148 us; speedup vs baseline: 1.3104x; 1.3104x over previous
//
#include <hip/hip_runtime.h>

#define N_NODES 50000
#define N_EDGES 800000
#define F 64
#define NROWS (N_NODES * 3)          // 150000 node-(v) rows
#define NPX (N_NODES * 3 * F)        // 9,600,000 floats (px_out size)

typedef float floatx4 __attribute__((ext_vector_type(4)));

__device__ __forceinline__ unsigned short f2bf(float f) {
  unsigned int u = __float_as_uint(f);
  return (unsigned short)((u + 0x7FFFu + ((u >> 16) & 1u)) >> 16);
}
__device__ __forceinline__ float bf2f(unsigned short h) {
  return __uint_as_float(((unsigned int)h) << 16);
}

// --- tiny 64x64 matmul pair: O = A @ B (row-major), one product per block ---
__global__ __launch_bounds__(256) void mm64_pair(
    const float* __restrict__ A0, const float* __restrict__ B0, float* __restrict__ O0,
    const float* __restrict__ A1, const float* __restrict__ B1, float* __restrict__ O1) {
  const float* A = (blockIdx.x == 0) ? A0 : A1;
  const float* B = (blockIdx.x == 0) ? B0 : B1;
  float* O = (blockIdx.x == 0) ? O0 : O1;
  __shared__ float As[64][65];
  __shared__ float Bs[64][65];
  int t = threadIdx.x;
  for (int k = 0; k < 16; ++k) {
    int idx = t + 256 * k;
    As[idx >> 6][idx & 63] = A[idx];
    Bs[idx >> 6][idx & 63] = B[idx];
  }
  __syncthreads();
  int g = t >> 2, f0 = (t & 3) * 16;
  float acc[16];
  #pragma unroll
  for (int j = 0; j < 16; ++j) acc[j] = 0.f;
  for (int k = 0; k < 64; ++k) {
    float a = As[g][k];
    #pragma unroll
    for (int j = 0; j < 16; ++j) acc[j] += a * Bs[k][f0 + j];
  }
  for (int j = 0; j < 16; ++j) O[g * 64 + f0 + j] = acc[j];
}

// --- node GEMM: yi[r,:] = px@Bi^T (f32) ; yjb[r,:] = px@Bj^T (bf16) ---
__global__ __launch_bounds__(256) void node_mm(
    const float* __restrict__ px, const float* __restrict__ Bi,
    const float* __restrict__ Bj, float* __restrict__ yi,
    unsigned short* __restrict__ yjb) {
  __shared__ float pxs[64][68];
  __shared__ float Bs[128][68];    // rows 0..63 = Bi, 64..127 = Bj
  int t = threadIdx.x;
  int r0 = blockIdx.x * 64;
  #pragma unroll
  for (int k = 0; k < 8; ++k) {
    int idx = t + 256 * k;
    int row = idx >> 4, c4 = (idx & 15) * 4;
    const float* src = (row < 64) ? (Bi + row * 64 + c4) : (Bj + (row - 64) * 64 + c4);
    *(float4*)&Bs[row][c4] = *(const float4*)src;
  }
  #pragma unroll
  for (int k = 0; k < 4; ++k) {
    int idx = t + 256 * k;
    int lr = idx >> 4, c4 = (idx & 15) * 4;
    float4 v = make_float4(0.f, 0.f, 0.f, 0.f);
    if (r0 + lr < NROWS) v = *(const float4*)(px + (size_t)(r0 + lr) * 64 + c4);
    *(float4*)&pxs[lr][c4] = v;
  }
  __syncthreads();
  int q = t & 31;
  int rg = t >> 5;
  float acc[8][4];
  #pragma unroll
  for (int r = 0; r < 8; ++r)
    #pragma unroll
    for (int j = 0; j < 4; ++j) acc[r][j] = 0.f;
  #pragma unroll 4
  for (int fc = 0; fc < 16; ++fc) {
    float4 b[4];
    #pragma unroll
    for (int j = 0; j < 4; ++j) b[j] = *(const float4*)&Bs[4 * q + j][fc * 4];
    #pragma unroll
    for (int r = 0; r < 8; ++r) {
      float4 p = *(const float4*)&pxs[rg * 8 + r][fc * 4];
      #pragma unroll
      for (int j = 0; j < 4; ++j)
        acc[r][j] += p.x * b[j].x + p.y * b[j].y + p.z * b[j].z + p.w * b[j].w;
    }
  }
  #pragma unroll
  for (int r = 0; r < 8; ++r) {
    int grow = r0 + rg * 8 + r;
    if (grow >= NROWS) continue;
    if (q < 16) {
      float4 v = make_float4(acc[r][0], acc[r][1], acc[r][2], acc[r][3]);
      *(float4*)(yi + (size_t)grow * 64 + q * 4) = v;
    } else {
      ushort4 h;
      h.x = f2bf(acc[r][0]); h.y = f2bf(acc[r][1]);
      h.z = f2bf(acc[r][2]); h.w = f2bf(acc[r][3]);
      *(ushort4*)(yjb + (size_t)grow * 64 + (q - 16) * 4) = h;
    }
  }
}

// --- CSR build step 1: histogram of idx_i ---
__global__ __launch_bounds__(256) void hist_kernel(
    const int* __restrict__ idx_i, int* __restrict__ cnt) {
  int e = blockIdx.x * 256 + threadIdx.x;
  if (e < N_EDGES) atomicAdd(&cnt[idx_i[e]], 1);
}

// --- CSR build step 2: exclusive scan, 8 elems/thread (single block) ---
__global__ __launch_bounds__(1024) void scan_kernel(
    const int* __restrict__ cnt, int* __restrict__ offs, int* __restrict__ cursor) {
  __shared__ int wsum[16];
  __shared__ int s_carry;
  int t = threadIdx.x, w = t >> 6, l = t & 63;
  if (t == 0) { s_carry = 0; offs[0] = 0; }
  __syncthreads();
  for (int base = 0; base < N_NODES; base += 8192) {
    int i0 = base + t * 8;
    int x[8];
    if (i0 + 7 < N_NODES) {
      int4 a = *(const int4*)(cnt + i0);
      int4 b = *(const int4*)(cnt + i0 + 4);
      x[0] = a.x; x[1] = a.y; x[2] = a.z; x[3] = a.w;
      x[4] = b.x; x[5] = b.y; x[6] = b.z; x[7] = b.w;
    } else {
      #pragma unroll
      for (int k = 0; k < 8; ++k) x[k] = (i0 + k < N_NODES) ? cnt[i0 + k] : 0;
    }
    int incl[8];
    int p = 0;
    #pragma unroll
    for (int k = 0; k < 8; ++k) { p += x[k]; incl[k] = p; }
    int tsum = p;
    int ts = tsum;
    #pragma unroll
    for (int off = 1; off < 64; off <<= 1) {
      int y = __shfl_up(ts, off, 64);
      if (l >= off) ts += y;
    }
    if (l == 63) wsum[w] = ts;
    __syncthreads();
    if (t < 16) {
      int ws_ = wsum[t];
      int si = ws_;
      #pragma unroll
      for (int off = 1; off < 16; off <<= 1) {
        int y = __shfl_up(si, off, 16);
        if (t >= off) si += y;
      }
      wsum[t] = si - ws_;          // exclusive wave base
    }
    __syncthreads();
    int basev = s_carry + wsum[w] + (ts - tsum);
    #pragma unroll
    for (int k = 0; k < 8; ++k) {
      int i = i0 + k;
      if (i < N_NODES) {
        int it = basev + incl[k];
        offs[i + 1] = it;
        cursor[i] = it - x[k];
      }
    }
    __syncthreads();
    if (t == 1023) s_carry = basev + tsum;
    __syncthreads();
  }
}

// --- CSR build step 3: scatter edge id + permuted idx_j + permuted diff ---
__global__ __launch_bounds__(256) void scatter_kernel(
    const int* __restrict__ idx_i, const int* __restrict__ idx_j,
    const float* __restrict__ diff, int* __restrict__ cursor,
    int* __restrict__ perm, int* __restrict__ pnj, float* __restrict__ pdiff) {
  int e = blockIdx.x * 256 + threadIdx.x;
  if (e < N_EDGES) {
    int pos = atomicAdd(&cursor[idx_i[e]], 1);
    perm[pos] = e;
    pnj[pos] = idx_j[e];
    pdiff[pos * 3 + 0] = diff[e * 3 + 0];
    pdiff[pos * 3 + 1] = diff[e * 3 + 1];
    pdiff[pos * 3 + 2] = diff[e * 3 + 2];
  }
}

// --- main: per (node,v) wave; pairs (p, p+4) per slot = 2x gathers in flight ---
__global__ __launch_bounds__(192) void node_edge_kernel(
    const int* __restrict__ offs, const int* __restrict__ perm,
    const int* __restrict__ pnj, const float* __restrict__ pdiff,
    const float* __restrict__ yi, const unsigned short* __restrict__ yjb,
    float* __restrict__ ix_out, float* __restrict__ px_out) {
  int n = blockIdx.x;
  int v = threadIdx.x >> 6;          // 0..2 (one wave per v)
  int lane = threadIdx.x & 63;
  int s = lane >> 4;                 // edge slot 0..3
  int fq = (lane & 15) * 4;          // feature quad
  int start = offs[n], end = offs[n + 1];
  size_t nrow = ((size_t)n * 3 + v) * 64 + fq;
  const float4 yiv = *(const float4*)(yi + nrow);
  float4 acc = make_float4(0.f, 0.f, 0.f, 0.f);
  float sum_d = 0.f;

  for (int p = start + s; p < end; p += 8) {
    int p2 = p + 4;
    bool has2 = (p2 < end);
    // resolve two independent edges (both chains issued back-to-back)
    int eA  = perm[p];
    int njA = pnj[p];
    float dA = pdiff[p * 3 + v];
    int eB = eA, njB = njA; float dB = 0.f;
    if (has2) { eB = perm[p2]; njB = pnj[p2]; dB = pdiff[p2 * 3 + v]; }
    const ushort4 wA = *(const ushort4*)(yjb + ((size_t)njA * 3 + v) * 64 + fq);
    const ushort4 wB = *(const ushort4*)(yjb + ((size_t)njB * 3 + v) * 64 + fq);
    float4 ya = make_float4(bf2f(wA.x), bf2f(wA.y), bf2f(wA.z), bf2f(wA.w));
    float4 yb = make_float4(bf2f(wB.x), bf2f(wB.y), bf2f(wB.z), bf2f(wB.w));
    acc.x += dA * ya.x + dB * yb.x;
    acc.y += dA * ya.y + dB * yb.y;
    acc.z += dA * ya.z + dB * yb.z;
    acc.w += dA * ya.w + dB * yb.w;
    sum_d += dA + dB;
    floatx4 rA;
    rA.x = dA * (yiv.x + ya.x); rA.y = dA * (yiv.y + ya.y);
    rA.z = dA * (yiv.z + ya.z); rA.w = dA * (yiv.w + ya.w);
    __builtin_nontemporal_store(rA, (floatx4*)(ix_out + ((size_t)eA * 3 + v) * 64 + fq));
    if (has2) {
      floatx4 rB;
      rB.x = dB * (yiv.x + yb.x); rB.y = dB * (yiv.y + yb.y);
      rB.z = dB * (yiv.z + yb.z); rB.w = dB * (yiv.w + yb.w);
      __builtin_nontemporal_store(rB, (floatx4*)(ix_out + ((size_t)eB * 3 + v) * 64 + fq));
    }
  }
  // reduce over the 4 edge slots (lanes xor 16, 32)
  #pragma unroll
  for (int mm = 16; mm < 64; mm <<= 1) {
    acc.x += __shfl_xor(acc.x, mm, 64);
    acc.y += __shfl_xor(acc.y, mm, 64);
    acc.z += __shfl_xor(acc.z, mm, 64);
    acc.w += __shfl_xor(acc.w, mm, 64);
    sum_d += __shfl_xor(sum_d, mm, 64);
  }
  if (s == 0) {
    float4 o = make_float4(yiv.x * sum_d + acc.x, yiv.y * sum_d + acc.y,
                           yiv.z * sum_d + acc.z, yiv.w * sum_d + acc.w);
    *(float4*)(px_out + nrow) = o;
  }
}

extern "C" void kernel_launch(void* const* d_in, const int* in_sizes, int n_in,
                              void* d_out, int out_size, void* d_ws, size_t ws_size,
                              hipStream_t stream) {
  const int*   idx_i = (const int*)d_in[0];
  const int*   idx_j = (const int*)d_in[1];
  const float* px    = (const float*)d_in[2];
  const float* diff  = (const float*)d_in[3];
  const float* W_pp  = (const float*)d_in[4];
  const float* W_i   = (const float*)d_in[5];
  const float* W_j   = (const float*)d_in[6];
  const float* W_ii  = (const float*)d_in[7];

  float* px_out = (float*)d_out;              // [50000,3,64]
  float* ix_out = (float*)d_out + NPX;        // [800000,3,64]

  float* ws = (float*)d_ws;
  float* yi = ws;                              // [150000,64] f32
  unsigned short* yjb = (unsigned short*)(yi + (size_t)NPX);   // [150000,64] bf16
  float* Ci = (float*)(yjb + (size_t)NPX);
  float* Cj = Ci + 4096;
  float* Bi = Cj + 4096;
  float* Bj = Bi + 4096;
  int* cnt    = (int*)(Bj + 4096);             // [50000]
  int* offs   = cnt + N_NODES;                 // [50001]
  int* cursor = offs + N_NODES + 1;            // [50000]
  int* perm   = cursor + N_NODES;              // [800000]
  int* pnj    = perm + N_EDGES;                // [800000]
  float* pdiff = (float*)(pnj + N_EDGES);      // [800000*3]

  (void)hipMemsetAsync(cnt, 0, N_NODES * sizeof(int), stream);

  // Bi = W_ii @ W_i @ W_pp ; Bj = W_ii @ W_j @ W_pp
  mm64_pair<<<2, 256, 0, stream>>>(W_ii, W_i, Ci, W_ii, W_j, Cj);
  mm64_pair<<<2, 256, 0, stream>>>(Ci, W_pp, Bi, Cj, W_pp, Bj);

  node_mm<<<(NROWS + 63) / 64, 256, 0, stream>>>(px, Bi, Bj, yi, yjb);

  hist_kernel<<<(N_EDGES + 255) / 256, 256, 0, stream>>>(idx_i, cnt);
  scan_kernel<<<1, 1024, 0, stream>>>(cnt, offs, cursor);
  scatter_kernel<<<(N_EDGES + 255) / 256, 256, 0, stream>>>(
      idx_i, idx_j, diff, cursor, perm, pnj, pdiff);

  node_edge_kernel<<<N_NODES, 192, 0, stream>>>(offs, perm, pnj, pdiff,
                                                yi, yjb, ix_out, px_out);
}